// Round 1
// baseline (1310.188 us; speedup 1.0000x reference)
//
#include <hip/hip_runtime.h>
#include <hip/hip_bf16.h>

#define NN 384
#define CZ 128
#define NH 4
#define NROWS (NN*NN)
#define LN_EPS 1e-5f
#define QSCALE 0.17677669529663687f  // 1/sqrt(32)

typedef unsigned short u16;
typedef unsigned int   u32;

__device__ __forceinline__ float bflo(u32 u) { union { u32 i; float f; } a; a.i = u << 16; return a.f; }
__device__ __forceinline__ float bfhi(u32 u) { union { u32 i; float f; } a; a.i = u & 0xffff0000u; return a.f; }
__device__ __forceinline__ u16 f2bf(float f) {
  union { float f; u32 i; } a; a.f = f;
  u32 r = a.i + 0x7fffu + ((a.i >> 16) & 1u);
  return (u16)(r >> 16);
}
__device__ __forceinline__ u32 pack2(float a, float b) { return (u32)f2bf(a) | ((u32)f2bf(b) << 16); }

// ---------------- Kernel 1: LayerNorm -> x(bf16), pair_bias^T (fp32) -------
// one wave per row r=(j,k); pbT layout [h][k][j] so attention reads coalesced
__global__ __launch_bounds__(256) void k_ln(const float* __restrict__ act,
    const float* __restrict__ lnw, const float* __restrict__ lnb,
    const float* __restrict__ w2d, u16* __restrict__ xbf, float* __restrict__ pbT) {
  int lane = threadIdx.x & 63;
  int r = blockIdx.x * 4 + (threadIdx.x >> 6);
  const float* a = act + (size_t)r * CZ;
  float a0 = a[lane], a1 = a[lane + 64];
  float s = a0 + a1, s2 = a0 * a0 + a1 * a1;
  #pragma unroll
  for (int m = 32; m >= 1; m >>= 1) { s += __shfl_xor(s, m, 64); s2 += __shfl_xor(s2, m, 64); }
  float mu = s * (1.0f / CZ);
  float inv = rsqrtf(s2 * (1.0f / CZ) - mu * mu + LN_EPS);
  float x0 = (a0 - mu) * inv * lnw[lane] + lnb[lane];
  float x1 = (a1 - mu) * inv * lnw[lane + 64] + lnb[lane + 64];
  xbf[(size_t)r * CZ + lane] = f2bf(x0);
  xbf[(size_t)r * CZ + lane + 64] = f2bf(x1);
  int j = r / NN, k = r - j * NN;
  #pragma unroll
  for (int h = 0; h < NH; ++h) {
    float p = x0 * w2d[h * CZ + lane] + x1 * w2d[h * CZ + lane + 64];
    #pragma unroll
    for (int m = 32; m >= 1; m >>= 1) p += __shfl_xor(p, m, 64);
    if (lane == 0) pbT[((size_t)h * NN + k) * NN + j] = p;
  }
}

// ---------------- Kernel 2: projections  out = x @ W^T  (bf16 out) ---------
// MAT: 0=q (scaled), 1=k, 2=v, 3=g (sigmoid(.+bg))
template<int MAT>
__global__ __launch_bounds__(256) void k_proj(const u16* __restrict__ x,
    const float* __restrict__ W, const float* __restrict__ bias,
    u16* __restrict__ out) {
  __shared__ __align__(16) u16 xs[64][130];   // pad to stride 130 (bank spread)
  __shared__ __align__(16) u16 wsm[128][130];
  int t = threadIdx.x;
  size_t row0 = (size_t)blockIdx.x * 64;
  for (int idx = t; idx < 128 * 64; idx += 256) {
    int e = idx >> 6, c2 = idx & 63;
    const float2 w = *(const float2*)&W[e * CZ + 2 * c2];
    *(u32*)&wsm[e][2 * c2] = pack2(w.x, w.y);
  }
  const u32* xsrc = (const u32*)(x + row0 * CZ);
  for (int idx = t; idx < 64 * 64; idx += 256) {
    int rr = idx >> 6, c2 = idx & 63;
    *(u32*)&xs[rr][2 * c2] = xsrc[rr * 64 + c2];
  }
  __syncthreads();
  int tx = t & 31, ty = t >> 5;  // cols tx*4..+3, rows ty*8..+7
  float acc[8][4];
  #pragma unroll
  for (int r = 0; r < 8; ++r)
    #pragma unroll
    for (int c = 0; c < 4; ++c) acc[r][c] = 0.f;
  for (int c2 = 0; c2 < 64; ++c2) {
    float xl[8], xh[8];
    #pragma unroll
    for (int r = 0; r < 8; ++r) {
      u32 u = *(const u32*)&xs[ty * 8 + r][2 * c2];
      xl[r] = bflo(u); xh[r] = bfhi(u);
    }
    #pragma unroll
    for (int c = 0; c < 4; ++c) {
      u32 u = *(const u32*)&wsm[tx * 4 + c][2 * c2];
      float wl = bflo(u), wh = bfhi(u);
      #pragma unroll
      for (int r = 0; r < 8; ++r) acc[r][c] += xl[r] * wl + xh[r] * wh;
    }
  }
  #pragma unroll
  for (int r = 0; r < 8; ++r) {
    size_t row = row0 + ty * 8 + r;
    float v0 = acc[r][0], v1 = acc[r][1], v2 = acc[r][2], v3 = acc[r][3];
    if (MAT == 0) { v0 *= QSCALE; v1 *= QSCALE; v2 *= QSCALE; v3 *= QSCALE; }
    if (MAT == 3) {
      int e = tx * 4;
      v0 = 1.f / (1.f + __expf(-(v0 + bias[e])));
      v1 = 1.f / (1.f + __expf(-(v1 + bias[e + 1])));
      v2 = 1.f / (1.f + __expf(-(v2 + bias[e + 2])));
      v3 = 1.f / (1.f + __expf(-(v3 + bias[e + 3])));
    }
    uint2 st; st.x = pack2(v0, v1); st.y = pack2(v2, v3);
    *(uint2*)&out[row * CZ + tx * 4] = st;
  }
}

// ---------------- Kernel 3: per-(i,h) row attention, online softmax --------
// block = 192 threads; thread owns query rows j=t and j=t+192
__global__ __launch_bounds__(192) void k_attn(const u16* __restrict__ q,
    const u16* __restrict__ kmat, const u16* __restrict__ vmat,
    const float* __restrict__ pbT, const float* __restrict__ mask,
    u16* __restrict__ o) {
  __shared__ __align__(16) u16 ks[NN][32];  // 24 KB
  __shared__ __align__(16) u16 vs[NN][32];  // 24 KB
  int i = blockIdx.x, h = blockIdx.y;
  int t = threadIdx.x;
  size_t base = ((size_t)i * NN) * CZ + h * 32;
  for (int idx = t; idx < NN * 4; idx += 192) {
    int r = idx >> 2, c = idx & 3;
    ((uint4*)&ks[r][0])[c] = ((const uint4*)(kmat + base + (size_t)r * CZ))[c];
    ((uint4*)&vs[r][0])[c] = ((const uint4*)(vmat + base + (size_t)r * CZ))[c];
  }
  __syncthreads();
  float qa[2][32];
  #pragma unroll
  for (int p = 0; p < 2; ++p) {
    const uint4* qs = (const uint4*)(q + base + (size_t)(t + p * 192) * CZ);
    #pragma unroll
    for (int c = 0; c < 4; ++c) {
      uint4 u = qs[c];
      qa[p][c*8+0] = bflo(u.x); qa[p][c*8+1] = bfhi(u.x);
      qa[p][c*8+2] = bflo(u.y); qa[p][c*8+3] = bfhi(u.y);
      qa[p][c*8+4] = bflo(u.z); qa[p][c*8+5] = bfhi(u.z);
      qa[p][c*8+6] = bflo(u.w); qa[p][c*8+7] = bfhi(u.w);
    }
  }
  float m0 = -1e30f, m1 = -1e30f, l0 = 0.f, l1 = 0.f;
  float acc0[32], acc1[32];
  #pragma unroll
  for (int d = 0; d < 32; ++d) { acc0[d] = 0.f; acc1[d] = 0.f; }
  const float* pb = pbT + (size_t)h * NN * NN;
  const float* mrow = mask + (size_t)i * NN;
  for (int kk = 0; kk < NN; ++kk) {
    float kf[32], vf[32];
    #pragma unroll
    for (int c = 0; c < 4; ++c) {
      uint4 u = ((const uint4*)&ks[kk][0])[c];  // broadcast read
      kf[c*8+0]=bflo(u.x); kf[c*8+1]=bfhi(u.x); kf[c*8+2]=bflo(u.y); kf[c*8+3]=bfhi(u.y);
      kf[c*8+4]=bflo(u.z); kf[c*8+5]=bfhi(u.z); kf[c*8+6]=bflo(u.w); kf[c*8+7]=bfhi(u.w);
    }
    float s0a=0,s0b=0,s0c=0,s0d=0, s1a=0,s1b=0,s1c=0,s1d=0;
    #pragma unroll
    for (int d = 0; d < 8; ++d) {
      s0a += qa[0][d]      * kf[d];
      s0b += qa[0][d + 8]  * kf[d + 8];
      s0c += qa[0][d + 16] * kf[d + 16];
      s0d += qa[0][d + 24] * kf[d + 24];
      s1a += qa[1][d]      * kf[d];
      s1b += qa[1][d + 8]  * kf[d + 8];
      s1c += qa[1][d + 16] * kf[d + 16];
      s1d += qa[1][d + 24] * kf[d + 24];
    }
    float mb = 1e9f * (mrow[kk] - 1.0f);
    float s0 = (s0a + s0b) + (s0c + s0d) + mb + pb[(size_t)kk * NN + t];
    float s1 = (s1a + s1b) + (s1c + s1d) + mb + pb[(size_t)kk * NN + t + 192];
    #pragma unroll
    for (int c = 0; c < 4; ++c) {
      uint4 u = ((const uint4*)&vs[kk][0])[c];
      vf[c*8+0]=bflo(u.x); vf[c*8+1]=bfhi(u.x); vf[c*8+2]=bflo(u.y); vf[c*8+3]=bfhi(u.y);
      vf[c*8+4]=bflo(u.z); vf[c*8+5]=bfhi(u.z); vf[c*8+6]=bflo(u.w); vf[c*8+7]=bfhi(u.w);
    }
    if (s0 > m0) {
      float rr = __expf(m0 - s0); m0 = s0; l0 = l0 * rr + 1.f;
      #pragma unroll
      for (int d = 0; d < 32; ++d) acc0[d] = acc0[d] * rr + vf[d];
    } else {
      float p = __expf(s0 - m0); l0 += p;
      #pragma unroll
      for (int d = 0; d < 32; ++d) acc0[d] += p * vf[d];
    }
    if (s1 > m1) {
      float rr = __expf(m1 - s1); m1 = s1; l1 = l1 * rr + 1.f;
      #pragma unroll
      for (int d = 0; d < 32; ++d) acc1[d] = acc1[d] * rr + vf[d];
    } else {
      float p = __expf(s1 - m1); l1 += p;
      #pragma unroll
      for (int d = 0; d < 32; ++d) acc1[d] += p * vf[d];
    }
  }
  float il0 = 1.f / l0, il1 = 1.f / l1;
  {
    uint4 st[4]; u32* pst = (u32*)st;
    #pragma unroll
    for (int c2 = 0; c2 < 16; ++c2) pst[c2] = pack2(acc0[2*c2]*il0, acc0[2*c2+1]*il0);
    uint4* dst = (uint4*)(o + base + (size_t)t * CZ);
    #pragma unroll
    for (int c = 0; c < 4; ++c) dst[c] = st[c];
  }
  {
    uint4 st[4]; u32* pst = (u32*)st;
    #pragma unroll
    for (int c2 = 0; c2 < 16; ++c2) pst[c2] = pack2(acc1[2*c2]*il1, acc1[2*c2+1]*il1);
    uint4* dst = (uint4*)(o + base + (size_t)(t + 192) * CZ);
    #pragma unroll
    for (int c = 0; c < 4; ++c) dst[c] = st[c];
  }
}

// ---------------- Kernel 4: out = (o*g) @ wo^T + bo  (fp32 out) ------------
__global__ __launch_bounds__(256) void k_out(const u16* __restrict__ o,
    const u16* __restrict__ g, const float* __restrict__ wo,
    const float* __restrict__ bo, float* __restrict__ out) {
  __shared__ __align__(16) u16 ts[64][130];
  __shared__ __align__(16) u16 wsm[128][130];
  int t = threadIdx.x;
  size_t row0 = (size_t)blockIdx.x * 64;
  for (int idx = t; idx < 128 * 64; idx += 256) {
    int cidx = idx >> 6, e2 = idx & 63;
    const float2 w = *(const float2*)&wo[cidx * CZ + 2 * e2];
    *(u32*)&wsm[cidx][2 * e2] = pack2(w.x, w.y);
  }
  for (int idx = t; idx < 64 * 64; idx += 256) {
    int rr = idx >> 6, e2 = idx & 63;
    u32 uo = ((const u32*)(o + (row0 + rr) * CZ))[e2];
    u32 ug = ((const u32*)(g + (row0 + rr) * CZ))[e2];
    *(u32*)&ts[rr][2 * e2] = pack2(bflo(uo) * bflo(ug), bfhi(uo) * bfhi(ug));
  }
  __syncthreads();
  int tx = t & 31, ty = t >> 5;
  float acc[8][4];
  #pragma unroll
  for (int r = 0; r < 8; ++r)
    #pragma unroll
    for (int c = 0; c < 4; ++c) acc[r][c] = 0.f;
  for (int e2 = 0; e2 < 64; ++e2) {
    float xl[8], xh[8];
    #pragma unroll
    for (int r = 0; r < 8; ++r) {
      u32 u = *(const u32*)&ts[ty * 8 + r][2 * e2];
      xl[r] = bflo(u); xh[r] = bfhi(u);
    }
    #pragma unroll
    for (int c = 0; c < 4; ++c) {
      u32 u = *(const u32*)&wsm[tx * 4 + c][2 * e2];
      float wl = bflo(u), wh = bfhi(u);
      #pragma unroll
      for (int r = 0; r < 8; ++r) acc[r][c] += xl[r] * wl + xh[r] * wh;
    }
  }
  #pragma unroll
  for (int r = 0; r < 8; ++r) {
    size_t row = row0 + ty * 8 + r;
    float4 v;
    v.x = acc[r][0] + bo[tx * 4 + 0];
    v.y = acc[r][1] + bo[tx * 4 + 1];
    v.z = acc[r][2] + bo[tx * 4 + 2];
    v.w = acc[r][3] + bo[tx * 4 + 3];
    *(float4*)&out[row * CZ + tx * 4] = v;
  }
}

extern "C" void kernel_launch(void* const* d_in, const int* in_sizes, int n_in,
                              void* d_out, int out_size, void* d_ws, size_t ws_size,
                              hipStream_t stream) {
  const float* act  = (const float*)d_in[0];
  const float* mask = (const float*)d_in[1];
  const float* ln_w = (const float*)d_in[2];
  const float* ln_b = (const float*)d_in[3];
  const float* w2d  = (const float*)d_in[4];
  const float* wq   = (const float*)d_in[5];
  const float* wk   = (const float*)d_in[6];
  const float* wv   = (const float*)d_in[7];
  const float* wg   = (const float*)d_in[8];
  const float* bg   = (const float*)d_in[9];
  const float* wo   = (const float*)d_in[10];
  const float* bo   = (const float*)d_in[11];
  float* out = (float*)d_out;

  // ws layout: x | q | k | v | g | o  (bf16, 37.75 MB each) + pbT (fp32 2.36 MB)
  // total ~229 MB
  char* ws = (char*)d_ws;
  const size_t sz = (size_t)NROWS * CZ * 2;
  u16* xbf = (u16*)ws;
  u16* qb  = (u16*)(ws + 1 * sz);
  u16* kb  = (u16*)(ws + 2 * sz);
  u16* vb  = (u16*)(ws + 3 * sz);
  u16* gb  = (u16*)(ws + 4 * sz);
  u16* ob  = (u16*)(ws + 5 * sz);
  float* pbT = (float*)(ws + 6 * sz);

  k_ln<<<NROWS / 4, 256, 0, stream>>>(act, ln_w, ln_b, w2d, xbf, pbT);
  k_proj<0><<<NROWS / 64, 256, 0, stream>>>(xbf, wq, nullptr, qb);
  k_proj<1><<<NROWS / 64, 256, 0, stream>>>(xbf, wk, nullptr, kb);
  k_proj<2><<<NROWS / 64, 256, 0, stream>>>(xbf, wv, nullptr, vb);
  k_proj<3><<<NROWS / 64, 256, 0, stream>>>(xbf, wg, bg, gb);
  dim3 ga(NN, NH);
  k_attn<<<ga, 192, 0, stream>>>(qb, kb, vb, pbT, mask, ob);
  k_out<<<NROWS / 64, 256, 0, stream>>>(ob, gb, wo, bo, out);
}

// Round 2
// 693.245 us; speedup vs baseline: 1.8899x; 1.8899x over previous
//
#include <hip/hip_runtime.h>
#include <hip/hip_bf16.h>

#define NN 384
#define CZ 128
#define NH 4
#define NROWS (NN*NN)
#define LN_EPS 1e-5f
#define LOG2E 1.4426950408889634f
#define QSCALE_L2 (0.17677669529663687f * 1.4426950408889634f)  // 1/sqrt(32) * log2(e)

typedef unsigned short u16;
typedef unsigned int   u32;
typedef __attribute__((ext_vector_type(8))) __bf16 bf16x8;
typedef __attribute__((ext_vector_type(16))) float f32x16;

__device__ __forceinline__ float bflo(u32 u) { union { u32 i; float f; } a; a.i = u << 16; return a.f; }
__device__ __forceinline__ float bfhi(u32 u) { union { u32 i; float f; } a; a.i = u & 0xffff0000u; return a.f; }
__device__ __forceinline__ u16 f2bf(float f) {
  union { float f; u32 i; } a; a.f = f;
  u32 r = a.i + 0x7fffu + ((a.i >> 16) & 1u);
  return (u16)(r >> 16);
}
__device__ __forceinline__ u32 pack2(float a, float b) { return (u32)f2bf(a) | ((u32)f2bf(b) << 16); }
__device__ __forceinline__ u32 cvtpk(float lo, float hi) {
  u32 r; asm("v_cvt_pk_bf16_f32 %0, %1, %2" : "=v"(r) : "v"(lo), "v"(hi)); return r;
}
__device__ __forceinline__ float exp2fast(float x) {
  float r; asm("v_exp_f32 %0, %1" : "=v"(r) : "v"(x)); return r;
}

// ---------------- Kernel 1: LayerNorm -> x(bf16), pair_bias (fp32, *log2e) --
// one wave per row r=(j,k); pb layout [h][j][k] == [h][r] flat
__global__ __launch_bounds__(256) void k_ln(const float* __restrict__ act,
    const float* __restrict__ lnw, const float* __restrict__ lnb,
    const float* __restrict__ w2d, u16* __restrict__ xbf, float* __restrict__ pb) {
  int lane = threadIdx.x & 63;
  int r = blockIdx.x * 4 + (threadIdx.x >> 6);
  const float* a = act + (size_t)r * CZ;
  float a0 = a[lane], a1 = a[lane + 64];
  float s = a0 + a1, s2 = a0 * a0 + a1 * a1;
  #pragma unroll
  for (int m = 32; m >= 1; m >>= 1) { s += __shfl_xor(s, m, 64); s2 += __shfl_xor(s2, m, 64); }
  float mu = s * (1.0f / CZ);
  float inv = rsqrtf(s2 * (1.0f / CZ) - mu * mu + LN_EPS);
  float x0 = (a0 - mu) * inv * lnw[lane] + lnb[lane];
  float x1 = (a1 - mu) * inv * lnw[lane + 64] + lnb[lane + 64];
  xbf[(size_t)r * CZ + lane] = f2bf(x0);
  xbf[(size_t)r * CZ + lane + 64] = f2bf(x1);
  #pragma unroll
  for (int h = 0; h < NH; ++h) {
    float p = x0 * w2d[h * CZ + lane] + x1 * w2d[h * CZ + lane + 64];
    #pragma unroll
    for (int m = 32; m >= 1; m >>= 1) p += __shfl_xor(p, m, 64);
    if (lane == 0) pb[(size_t)h * NROWS + r] = p * LOG2E;
  }
}

// ---------------- Kernel 2: projections  out = x @ W^T  (bf16 out) ---------
// MAT: 0=q (scaled by QSCALE*log2e), 1=k, 2=v (TRANSPOSED out vT[e][row]), 3=g
template<int MAT>
__global__ __launch_bounds__(256) void k_proj(const u16* __restrict__ x,
    const float* __restrict__ W, const float* __restrict__ bias,
    u16* __restrict__ out) {
  __shared__ __align__(16) u16 xs[64][130];
  __shared__ __align__(16) u16 wsm[128][130];
  int t = threadIdx.x;
  size_t row0 = (size_t)blockIdx.x * 64;
  for (int idx = t; idx < 128 * 64; idx += 256) {
    int e = idx >> 6, c2 = idx & 63;
    const float2 w = *(const float2*)&W[e * CZ + 2 * c2];
    *(u32*)&wsm[e][2 * c2] = pack2(w.x, w.y);
  }
  const u32* xsrc = (const u32*)(x + row0 * CZ);
  for (int idx = t; idx < 64 * 64; idx += 256) {
    int rr = idx >> 6, c2 = idx & 63;
    *(u32*)&xs[rr][2 * c2] = xsrc[rr * 64 + c2];
  }
  __syncthreads();
  int tx = t & 31, ty = t >> 5;  // cols tx*4..+3, rows ty*8..+7
  float acc[8][4];
  #pragma unroll
  for (int r = 0; r < 8; ++r)
    #pragma unroll
    for (int c = 0; c < 4; ++c) acc[r][c] = 0.f;
  for (int c2 = 0; c2 < 64; ++c2) {
    float xl[8], xh[8];
    #pragma unroll
    for (int r = 0; r < 8; ++r) {
      u32 u = *(const u32*)&xs[ty * 8 + r][2 * c2];
      xl[r] = bflo(u); xh[r] = bfhi(u);
    }
    #pragma unroll
    for (int c = 0; c < 4; ++c) {
      u32 u = *(const u32*)&wsm[tx * 4 + c][2 * c2];
      float wl = bflo(u), wh = bfhi(u);
      #pragma unroll
      for (int r = 0; r < 8; ++r) acc[r][c] += xl[r] * wl + xh[r] * wh;
    }
  }
  if (MAT == 2) {
    // transposed store: vT[e][row], e = tx*4+c
    #pragma unroll
    for (int c = 0; c < 4; ++c) {
      int e = tx * 4 + c;
      uint4 st;
      st.x = pack2(acc[0][c], acc[1][c]);
      st.y = pack2(acc[2][c], acc[3][c]);
      st.z = pack2(acc[4][c], acc[5][c]);
      st.w = pack2(acc[6][c], acc[7][c]);
      *(uint4*)&out[(size_t)e * NROWS + row0 + ty * 8] = st;
    }
  } else {
    #pragma unroll
    for (int r = 0; r < 8; ++r) {
      size_t row = row0 + ty * 8 + r;
      float v0 = acc[r][0], v1 = acc[r][1], v2 = acc[r][2], v3 = acc[r][3];
      if (MAT == 0) { v0 *= QSCALE_L2; v1 *= QSCALE_L2; v2 *= QSCALE_L2; v3 *= QSCALE_L2; }
      if (MAT == 3) {
        int e = tx * 4;
        v0 = 1.f / (1.f + __expf(-(v0 + bias[e])));
        v1 = 1.f / (1.f + __expf(-(v1 + bias[e + 1])));
        v2 = 1.f / (1.f + __expf(-(v2 + bias[e + 2])));
        v3 = 1.f / (1.f + __expf(-(v3 + bias[e + 3])));
      }
      uint2 st; st.x = pack2(v0, v1); st.y = pack2(v2, v3);
      *(uint2*)&out[row * CZ + tx * 4] = st;
    }
  }
}

// ---------------- Kernel 3: MFMA row attention, online softmax -------------
// block (i,h), 256 threads = 4 waves; wave owns 96 query rows (3 j-frags of 32)
// Swapped QK^T: S^T[k][j] via mfma(K, Q^T); C layout col=j(l&31),
// row k_local = (r&3)+8*(r>>2)+4*(l>>5). PV: O^T = V^T . P^T.
__global__ __launch_bounds__(256) void k_attn(const u16* __restrict__ q,
    const u16* __restrict__ kmat, const u16* __restrict__ vT,
    const float* __restrict__ pb, const float* __restrict__ mask,
    u16* __restrict__ o) {
  __shared__ __align__(16) u16 ks[384 * 40];  // K rows padded to 40 bf16 (30720 B)
  __shared__ __align__(16) u16 vs[32 * 392];  // V^T rows padded to 392 bf16 (25088 B)
  int i = blockIdx.x, h = blockIdx.y;
  int t = threadIdx.x;
  // stage K [384][32] -> ks[row*40 + d]
  {
    const u16* src = kmat + (size_t)i * 384 * CZ + h * 32;
    for (int idx = t; idx < 384 * 4; idx += 256) {
      int row = idx >> 2, c = idx & 3;
      uint4 u = *(const uint4*)(src + (size_t)row * CZ + c * 8);
      *(uint4*)&ks[row * 40 + c * 8] = u;
    }
  }
  // stage V^T [32][384] -> vs[d*392 + k]
  {
    const u16* src = vT + (size_t)(h * 32) * NROWS + (size_t)i * 384;
    for (int idx = t; idx < 32 * 48; idx += 256) {
      int d = idx / 48, c = idx % 48;
      uint4 u = *(const uint4*)(src + (size_t)d * NROWS + c * 8);
      *(uint4*)&vs[d * 392 + c * 8] = u;
    }
  }
  __syncthreads();
  int lane = t & 63, wid = t >> 6;
  int jl = lane & 31, g = lane >> 5;
  int j0 = wid * 96;
  // Q B-frags: B[d][j]=Q[j][d]; lane reads Q[j0+jf*32+jl][8g+16s .. +7]
  bf16x8 qf[3][2];
  const u16* qbase = q + (size_t)i * 384 * CZ + h * 32;
  #pragma unroll
  for (int jf = 0; jf < 3; ++jf)
    #pragma unroll
    for (int s = 0; s < 2; ++s)
      qf[jf][s] = *(const bf16x8*)(qbase + (size_t)(j0 + jf * 32 + jl) * CZ + g * 8 + s * 16);

  f32x16 oacc[3];
  #pragma unroll
  for (int jf = 0; jf < 3; ++jf)
    #pragma unroll
    for (int r = 0; r < 16; ++r) oacc[jf][r] = 0.f;
  float mrun[3] = {-3e38f, -3e38f, -3e38f};
  float lrun[3] = {0.f, 0.f, 0.f};
  const float* pbh = pb + (size_t)h * NROWS;
  const float* mrow = mask + (size_t)i * NN;

  for (int k0 = 0; k0 < NN; k0 += 32) {
    // mask bias (base-2 domain), k_local = (r&3)+8*(r>>2)+4g
    float mbf[16];
    #pragma unroll
    for (int m4 = 0; m4 < 4; ++m4) {
      float4 mm = *(const float4*)(mrow + k0 + 8 * m4 + 4 * g);
      mbf[m4 * 4 + 0] = (mm.x - 1.f) * (1e9f * LOG2E);
      mbf[m4 * 4 + 1] = (mm.y - 1.f) * (1e9f * LOG2E);
      mbf[m4 * 4 + 2] = (mm.z - 1.f) * (1e9f * LOG2E);
      mbf[m4 * 4 + 3] = (mm.w - 1.f) * (1e9f * LOG2E);
    }
    // K A-frags (row=k, kdim=d): 2 d-slices
    bf16x8 ka0 = *(const bf16x8*)&ks[(k0 + jl) * 40 + 8 * g];
    bf16x8 ka1 = *(const bf16x8*)&ks[(k0 + jl) * 40 + 8 * g + 16];
    // V^T A-frags (row=d, kdim=k): 2 k-slices
    bf16x8 va0 = *(const bf16x8*)&vs[jl * 392 + k0 + 8 * g];
    bf16x8 va1 = *(const bf16x8*)&vs[jl * 392 + k0 + 16 + 8 * g];
    #pragma unroll
    for (int jf = 0; jf < 3; ++jf) {
      f32x16 sac;
      #pragma unroll
      for (int r = 0; r < 16; ++r) sac[r] = 0.f;
      sac = __builtin_amdgcn_mfma_f32_32x32x16_bf16(ka0, qf[jf][0], sac, 0, 0, 0);
      sac = __builtin_amdgcn_mfma_f32_32x32x16_bf16(ka1, qf[jf][1], sac, 0, 0, 0);
      // add pair bias (pre-scaled by log2e) + mask bias
      const float* pbj = pbh + (size_t)(j0 + jf * 32 + jl) * NN + k0 + 4 * g;
      float4 pbv[4];
      #pragma unroll
      for (int m4 = 0; m4 < 4; ++m4) pbv[m4] = *(const float4*)(pbj + 8 * m4);
      float s[16];
      #pragma unroll
      for (int r = 0; r < 16; ++r)
        s[r] = sac[r] + (&pbv[r >> 2].x)[r & 3] + mbf[r];
      // tile max across this lane's 16 k + partner lane (same j, other 16 k)
      float tmax = s[0];
      #pragma unroll
      for (int r = 1; r < 16; ++r) tmax = fmaxf(tmax, s[r]);
      tmax = fmaxf(tmax, __shfl_xor(tmax, 32, 64));
      float mold = mrun[jf];
      float mnew = fmaxf(mold, tmax);
      float p[16];
      #pragma unroll
      for (int r = 0; r < 16; ++r) p[r] = exp2fast(s[r] - mnew);
      float psum = ((p[0]+p[1])+(p[2]+p[3])) + ((p[4]+p[5])+(p[6]+p[7]))
                 + ((p[8]+p[9])+(p[10]+p[11])) + ((p[12]+p[13])+(p[14]+p[15]));
      if (!__all(mnew == mold)) {
        float rsc = exp2fast(mold - mnew);
        mrun[jf] = mnew;
        lrun[jf] = lrun[jf] * rsc + psum;
        #pragma unroll
        for (int r = 0; r < 16; ++r) oacc[jf][r] *= rsc;
      } else {
        lrun[jf] += psum;
      }
      // pack P to bf16 and build PV B-operand (B[k][j], kdim = 8g+i per slice)
      u32 A01 = cvtpk(p[0], p[1]),   A23 = cvtpk(p[2], p[3]);
      u32 B01 = cvtpk(p[4], p[5]),   B23 = cvtpk(p[6], p[7]);
      u32 C01 = cvtpk(p[8], p[9]),   C23 = cvtpk(p[10], p[11]);
      u32 D01 = cvtpk(p[12], p[13]), D23 = cvtpk(p[14], p[15]);
      u32 A01x = __shfl_xor(A01, 32, 64), A23x = __shfl_xor(A23, 32, 64);
      u32 B01x = __shfl_xor(B01, 32, 64), B23x = __shfl_xor(B23, 32, 64);
      u32 C01x = __shfl_xor(C01, 32, 64), C23x = __shfl_xor(C23, 32, 64);
      u32 D01x = __shfl_xor(D01, 32, 64), D23x = __shfl_xor(D23, 32, 64);
      union { u32 w[4]; bf16x8 v; } b0, b1;
      b0.w[0] = g ? B01x : A01;  b0.w[1] = g ? B23x : A23;
      b0.w[2] = g ? B01  : A01x; b0.w[3] = g ? B23  : A23x;
      b1.w[0] = g ? D01x : C01;  b1.w[1] = g ? D23x : C23;
      b1.w[2] = g ? D01  : C01x; b1.w[3] = g ? D23  : C23x;
      oacc[jf] = __builtin_amdgcn_mfma_f32_32x32x16_bf16(va0, b0.v, oacc[jf], 0, 0, 0);
      oacc[jf] = __builtin_amdgcn_mfma_f32_32x32x16_bf16(va1, b1.v, oacc[jf], 0, 0, 0);
    }
  }
  // epilogue: combine l across lane pair, normalize, store O (rows j, cols h*32+d)
  #pragma unroll
  for (int jf = 0; jf < 3; ++jf) {
    float lt = lrun[jf] + __shfl_xor(lrun[jf], 32, 64);
    float inv = 1.f / lt;
    u16* dst = o + (size_t)(i * 384 + j0 + jf * 32 + jl) * CZ + h * 32 + 4 * g;
    #pragma unroll
    for (int q4 = 0; q4 < 4; ++q4) {
      uint2 st;
      st.x = cvtpk(oacc[jf][4 * q4 + 0] * inv, oacc[jf][4 * q4 + 1] * inv);
      st.y = cvtpk(oacc[jf][4 * q4 + 2] * inv, oacc[jf][4 * q4 + 3] * inv);
      *(uint2*)(dst + 8 * q4) = st;
    }
  }
}

// ---------------- Kernel 4: out = (o*g) @ wo^T + bo  (fp32 out) ------------
__global__ __launch_bounds__(256) void k_out(const u16* __restrict__ o,
    const u16* __restrict__ g, const float* __restrict__ wo,
    const float* __restrict__ bo, float* __restrict__ out) {
  __shared__ __align__(16) u16 ts[64][130];
  __shared__ __align__(16) u16 wsm[128][130];
  int t = threadIdx.x;
  size_t row0 = (size_t)blockIdx.x * 64;
  for (int idx = t; idx < 128 * 64; idx += 256) {
    int cidx = idx >> 6, e2 = idx & 63;
    const float2 w = *(const float2*)&wo[cidx * CZ + 2 * e2];
    *(u32*)&wsm[cidx][2 * e2] = pack2(w.x, w.y);
  }
  for (int idx = t; idx < 64 * 64; idx += 256) {
    int rr = idx >> 6, e2 = idx & 63;
    u32 uo = ((const u32*)(o + (row0 + rr) * CZ))[e2];
    u32 ug = ((const u32*)(g + (row0 + rr) * CZ))[e2];
    *(u32*)&ts[rr][2 * e2] = pack2(bflo(uo) * bflo(ug), bfhi(uo) * bfhi(ug));
  }
  __syncthreads();
  int tx = t & 31, ty = t >> 5;
  float acc[8][4];
  #pragma unroll
  for (int r = 0; r < 8; ++r)
    #pragma unroll
    for (int c = 0; c < 4; ++c) acc[r][c] = 0.f;
  for (int e2 = 0; e2 < 64; ++e2) {
    float xl[8], xh[8];
    #pragma unroll
    for (int r = 0; r < 8; ++r) {
      u32 u = *(const u32*)&ts[ty * 8 + r][2 * e2];
      xl[r] = bflo(u); xh[r] = bfhi(u);
    }
    #pragma unroll
    for (int c = 0; c < 4; ++c) {
      u32 u = *(const u32*)&wsm[tx * 4 + c][2 * e2];
      float wl = bflo(u), wh = bfhi(u);
      #pragma unroll
      for (int r = 0; r < 8; ++r) acc[r][c] += xl[r] * wl + xh[r] * wh;
    }
  }
  #pragma unroll
  for (int r = 0; r < 8; ++r) {
    size_t row = row0 + ty * 8 + r;
    float4 v;
    v.x = acc[r][0] + bo[tx * 4 + 0];
    v.y = acc[r][1] + bo[tx * 4 + 1];
    v.z = acc[r][2] + bo[tx * 4 + 2];
    v.w = acc[r][3] + bo[tx * 4 + 3];
    *(float4*)&out[row * CZ + tx * 4] = v;
  }
}

extern "C" void kernel_launch(void* const* d_in, const int* in_sizes, int n_in,
                              void* d_out, int out_size, void* d_ws, size_t ws_size,
                              hipStream_t stream) {
  const float* act  = (const float*)d_in[0];
  const float* mask = (const float*)d_in[1];
  const float* ln_w = (const float*)d_in[2];
  const float* ln_b = (const float*)d_in[3];
  const float* w2d  = (const float*)d_in[4];
  const float* wq   = (const float*)d_in[5];
  const float* wk   = (const float*)d_in[6];
  const float* wv   = (const float*)d_in[7];
  const float* wg   = (const float*)d_in[8];
  const float* bg   = (const float*)d_in[9];
  const float* wo   = (const float*)d_in[10];
  const float* bo   = (const float*)d_in[11];
  float* out = (float*)d_out;

  // ws: x | q | k | vT | g | o (bf16, 37.75 MB each) + pb (fp32 2.36 MB)
  char* ws = (char*)d_ws;
  const size_t sz = (size_t)NROWS * CZ * 2;
  u16* xbf = (u16*)ws;
  u16* qb  = (u16*)(ws + 1 * sz);
  u16* kb  = (u16*)(ws + 2 * sz);
  u16* vTb = (u16*)(ws + 3 * sz);
  u16* gb  = (u16*)(ws + 4 * sz);
  u16* ob  = (u16*)(ws + 5 * sz);
  float* pbf = (float*)(ws + 6 * sz);

  k_ln<<<NROWS / 4, 256, 0, stream>>>(act, ln_w, ln_b, w2d, xbf, pbf);
  k_proj<0><<<NROWS / 64, 256, 0, stream>>>(xbf, wq, nullptr, qb);
  k_proj<1><<<NROWS / 64, 256, 0, stream>>>(xbf, wk, nullptr, kb);
  k_proj<2><<<NROWS / 64, 256, 0, stream>>>(xbf, wv, nullptr, vTb);
  k_proj<3><<<NROWS / 64, 256, 0, stream>>>(xbf, wg, bg, gb);
  dim3 ga(NN, NH);
  k_attn<<<ga, 256, 0, stream>>>(qb, kb, vTb, pbf, mask, ob);
  k_out<<<NROWS / 64, 256, 0, stream>>>(ob, gb, wo, bo, out);
}

// Round 3
// 389.010 us; speedup vs baseline: 3.3680x; 1.7821x over previous
//
#include <hip/hip_runtime.h>
#include <hip/hip_bf16.h>

#define NN 384
#define CZ 128
#define NH 4
#define NROWS (NN*NN)
#define LN_EPS 1e-5f
#define LOG2E 1.4426950408889634f
#define QSCALE_L2 (0.17677669529663687f * 1.4426950408889634f)  // 1/sqrt(32) * log2(e)

typedef unsigned short u16;
typedef unsigned int   u32;
typedef __attribute__((ext_vector_type(8))) __bf16 bf16x8;
typedef __attribute__((ext_vector_type(16))) float f32x16;

__device__ __forceinline__ float bflo(u32 u) { union { u32 i; float f; } a; a.i = u << 16; return a.f; }
__device__ __forceinline__ float bfhi(u32 u) { union { u32 i; float f; } a; a.i = u & 0xffff0000u; return a.f; }
__device__ __forceinline__ u16 f2bf(float f) {
  union { float f; u32 i; } a; a.f = f;
  u32 r = a.i + 0x7fffu + ((a.i >> 16) & 1u);
  return (u16)(r >> 16);
}
__device__ __forceinline__ u32 cvtpk(float lo, float hi) {
  u32 r; asm("v_cvt_pk_bf16_f32 %0, %1, %2" : "=v"(r) : "v"(lo), "v"(hi)); return r;
}
__device__ __forceinline__ float exp2fast(float x) {
  float r; asm("v_exp_f32 %0, %1" : "=v"(r) : "v"(x)); return r;
}
__device__ __forceinline__ float sigm(float x) {
  return 1.f / (1.f + exp2fast(-x * LOG2E));
}

// ---------------- Kernel 1: LayerNorm -> x(bf16), pair_bias (bf16, *log2e) --
__global__ __launch_bounds__(256) void k_ln(const float* __restrict__ act,
    const float* __restrict__ lnw, const float* __restrict__ lnb,
    const float* __restrict__ w2d, u16* __restrict__ xbf, u16* __restrict__ pb) {
  int lane = threadIdx.x & 63;
  int r = blockIdx.x * 4 + (threadIdx.x >> 6);
  const float* a = act + (size_t)r * CZ;
  float a0 = a[lane], a1 = a[lane + 64];
  float s = a0 + a1, s2 = a0 * a0 + a1 * a1;
  #pragma unroll
  for (int m = 32; m >= 1; m >>= 1) { s += __shfl_xor(s, m, 64); s2 += __shfl_xor(s2, m, 64); }
  float mu = s * (1.0f / CZ);
  float inv = rsqrtf(s2 * (1.0f / CZ) - mu * mu + LN_EPS);
  float x0 = (a0 - mu) * inv * lnw[lane] + lnb[lane];
  float x1 = (a1 - mu) * inv * lnw[lane + 64] + lnb[lane + 64];
  xbf[(size_t)r * CZ + lane] = f2bf(x0);
  xbf[(size_t)r * CZ + lane + 64] = f2bf(x1);
  #pragma unroll
  for (int h = 0; h < NH; ++h) {
    float p = x0 * w2d[h * CZ + lane] + x1 * w2d[h * CZ + lane + 64];
    #pragma unroll
    for (int m = 32; m >= 1; m >>= 1) p += __shfl_xor(p, m, 64);
    if (lane == 0) pb[(size_t)h * NROWS + r] = f2bf(p * LOG2E);
  }
}

// ---------------- Kernel 2: fused MFMA projections ------------------------
// Persistent: grid=256, 9 row-tiles of 64 per block. Wave w owns mat w
// (0=q,1=k,2=v->vT,3=g). All 4 weight mats bf16 in LDS (swizzled), x tile
// swizzled. q/k/g: mfma(W,x^T) -> 8B row-major stores; v: mfma(x,W^T).
__global__ __launch_bounds__(256) void k_projf(const u16* __restrict__ x,
    const float* __restrict__ wq, const float* __restrict__ wk,
    const float* __restrict__ wv, const float* __restrict__ wg,
    const float* __restrict__ bg,
    u16* __restrict__ qb, u16* __restrict__ kb,
    u16* __restrict__ vT, u16* __restrict__ gb) {
  __shared__ __align__(16) u16 wlds[4][128][128];  // 128 KB
  __shared__ __align__(16) u16 xlds[64][128];      // 16 KB
  int t = threadIdx.x;
  int lane = t & 63, wid = t >> 6;
  int jl = lane & 31, g = lane >> 5;
  size_t tile0 = (size_t)blockIdx.x * 9;

  // prologue: issue x tile 0 loads first (long latency)
  uint4 xr[4];
  {
    const uint4* src = (const uint4*)(x + tile0 * 64 * CZ);
    #pragma unroll
    for (int p = 0; p < 4; ++p) xr[p] = src[t + p * 256];
  }
  // stage all 4 weight mats, fp32 -> bf16, swizzled slots (q pre-scaled)
  #pragma unroll
  for (int m = 0; m < 4; ++m) {
    const float* W = (m == 0) ? wq : (m == 1) ? wk : (m == 2) ? wv : wg;
    float sc = (m == 0) ? QSCALE_L2 : 1.f;
    #pragma unroll
    for (int it = 0; it < 8; ++it) {
      int idx = t + it * 256;
      int e = idx >> 4, s = idx & 15;
      float4 f0 = *(const float4*)&W[e * CZ + s * 8];
      float4 f1 = *(const float4*)&W[e * CZ + s * 8 + 4];
      uint4 st;
      st.x = cvtpk(f0.x * sc, f0.y * sc); st.y = cvtpk(f0.z * sc, f0.w * sc);
      st.z = cvtpk(f1.x * sc, f1.y * sc); st.w = cvtpk(f1.z * sc, f1.w * sc);
      *(uint4*)&wlds[m][e][(s ^ (e & 15)) * 8] = st;
    }
  }

  for (int it = 0; it < 9; ++it) {
    __syncthreads();  // prev compute done reading xlds
    #pragma unroll
    for (int p = 0; p < 4; ++p) {
      int q = t + p * 256; int r = q >> 4, s = q & 15;
      *(uint4*)&xlds[r][(s ^ (r & 15)) * 8] = xr[p];
    }
    __syncthreads();  // xlds (and, first iter, wlds) visible
    if (it < 8) {     // T14: issue next tile's loads before compute
      const uint4* src = (const uint4*)(x + (tile0 + it + 1) * 64 * CZ);
      #pragma unroll
      for (int p = 0; p < 4; ++p) xr[p] = src[t + p * 256];
    }
    size_t row0 = (tile0 + it) * 64;

    f32x16 acc[2][4];
    #pragma unroll
    for (int rf = 0; rf < 2; ++rf)
      #pragma unroll
      for (int ef = 0; ef < 4; ++ef)
        #pragma unroll
        for (int i = 0; i < 16; ++i) acc[rf][ef][i] = 0.f;

    if (wid == 2) {  // ----- v: mfma(x, W^T) -> C[row][e], vT store -----
      #pragma unroll
      for (int ks = 0; ks < 8; ++ks) {
        bf16x8 xa[2], wf[4];
        #pragma unroll
        for (int rf = 0; rf < 2; ++rf) {
          int r = rf * 32 + jl;
          xa[rf] = *(const bf16x8*)&xlds[r][((2 * ks + g) ^ (r & 15)) * 8];
        }
        #pragma unroll
        for (int ef = 0; ef < 4; ++ef) {
          int e = ef * 32 + jl;
          wf[ef] = *(const bf16x8*)&wlds[2][e][((2 * ks + g) ^ (e & 15)) * 8];
        }
        #pragma unroll
        for (int rf = 0; rf < 2; ++rf)
          #pragma unroll
          for (int ef = 0; ef < 4; ++ef)
            acc[rf][ef] = __builtin_amdgcn_mfma_f32_32x32x16_bf16(xa[rf], wf[ef], acc[rf][ef], 0, 0, 0);
      }
      #pragma unroll
      for (int rf = 0; rf < 2; ++rf)
        #pragma unroll
        for (int ef = 0; ef < 4; ++ef) {
          int e = ef * 32 + jl;
          u16* dst = vT + (size_t)e * NROWS + row0 + rf * 32 + 4 * g;
          #pragma unroll
          for (int rr = 0; rr < 4; ++rr) {
            uint2 st;
            st.x = cvtpk(acc[rf][ef][4 * rr + 0], acc[rf][ef][4 * rr + 1]);
            st.y = cvtpk(acc[rf][ef][4 * rr + 2], acc[rf][ef][4 * rr + 3]);
            *(uint2*)(dst + 8 * rr) = st;
          }
        }
    } else {  // ----- q/k/g: mfma(W, x^T) -> C[e][row], row-major store -----
      int m = wid;  // 0,1,3
      #pragma unroll
      for (int ks = 0; ks < 8; ++ks) {
        bf16x8 xa[2], wf[4];
        #pragma unroll
        for (int rf = 0; rf < 2; ++rf) {
          int r = rf * 32 + jl;
          xa[rf] = *(const bf16x8*)&xlds[r][((2 * ks + g) ^ (r & 15)) * 8];
        }
        #pragma unroll
        for (int ef = 0; ef < 4; ++ef) {
          int e = ef * 32 + jl;
          wf[ef] = *(const bf16x8*)&wlds[m][e][((2 * ks + g) ^ (e & 15)) * 8];
        }
        #pragma unroll
        for (int rf = 0; rf < 2; ++rf)
          #pragma unroll
          for (int ef = 0; ef < 4; ++ef)
            acc[rf][ef] = __builtin_amdgcn_mfma_f32_32x32x16_bf16(wf[ef], xa[rf], acc[rf][ef], 0, 0, 0);
      }
      u16* ob = (wid == 0) ? qb : (wid == 1) ? kb : gb;
      #pragma unroll
      for (int rf = 0; rf < 2; ++rf) {
        size_t row = row0 + rf * 32 + jl;
        #pragma unroll
        for (int ef = 0; ef < 4; ++ef) {
          u16* dst = ob + row * CZ + ef * 32 + 4 * g;
          #pragma unroll
          for (int rr = 0; rr < 4; ++rr) {
            float v0 = acc[rf][ef][4 * rr + 0], v1 = acc[rf][ef][4 * rr + 1];
            float v2 = acc[rf][ef][4 * rr + 2], v3 = acc[rf][ef][4 * rr + 3];
            if (wid == 3) {
              float4 bv = *(const float4*)&bg[ef * 32 + 8 * rr + 4 * g];
              v0 = sigm(v0 + bv.x); v1 = sigm(v1 + bv.y);
              v2 = sigm(v2 + bv.z); v3 = sigm(v3 + bv.w);
            }
            uint2 st; st.x = cvtpk(v0, v1); st.y = cvtpk(v2, v3);
            *(uint2*)(dst + 8 * rr) = st;
          }
        }
      }
    }
  }
}

// ---------------- Kernel 3: MFMA row attention, online softmax -------------
__global__ __launch_bounds__(256) void k_attn(const u16* __restrict__ q,
    const u16* __restrict__ kmat, const u16* __restrict__ vT,
    const u16* __restrict__ pb, const float* __restrict__ mask,
    u16* __restrict__ o) {
  __shared__ __align__(16) u16 ks[384 * 40];  // K rows padded to 40 bf16
  __shared__ __align__(16) u16 vs[32 * 392];  // V^T rows padded to 392 bf16
  int i = blockIdx.x, h = blockIdx.y;
  int t = threadIdx.x;
  size_t base = ((size_t)i * 384) * CZ + h * 32;
  {
    const u16* src = kmat + base;
    for (int idx = t; idx < 384 * 4; idx += 256) {
      int row = idx >> 2, c = idx & 3;
      *(uint4*)&ks[row * 40 + c * 8] = *(const uint4*)(src + (size_t)row * CZ + c * 8);
    }
  }
  {
    const u16* src = vT + (size_t)(h * 32) * NROWS + (size_t)i * 384;
    for (int idx = t; idx < 32 * 48; idx += 256) {
      int d = idx / 48, c = idx % 48;
      *(uint4*)&vs[d * 392 + c * 8] = *(const uint4*)(src + (size_t)d * NROWS + c * 8);
    }
  }
  __syncthreads();
  int lane = t & 63, wid = t >> 6;
  int jl = lane & 31, g = lane >> 5;
  int j0 = wid * 96;
  bf16x8 qf[3][2];
  const u16* qbase = q + base;
  #pragma unroll
  for (int jf = 0; jf < 3; ++jf)
    #pragma unroll
    for (int s = 0; s < 2; ++s)
      qf[jf][s] = *(const bf16x8*)(qbase + (size_t)(j0 + jf * 32 + jl) * CZ + g * 8 + s * 16);

  f32x16 oacc[3];
  #pragma unroll
  for (int jf = 0; jf < 3; ++jf)
    #pragma unroll
    for (int r = 0; r < 16; ++r) oacc[jf][r] = 0.f;
  float mrun[3] = {-3e38f, -3e38f, -3e38f};
  float lrun[3] = {0.f, 0.f, 0.f};
  const u16* pbh = pb + (size_t)h * NROWS;
  const float* mrow = mask + (size_t)i * NN;

  for (int k0 = 0; k0 < NN; k0 += 32) {
    float mbf[16];
    #pragma unroll
    for (int m4 = 0; m4 < 4; ++m4) {
      float4 mm = *(const float4*)(mrow + k0 + 8 * m4 + 4 * g);
      mbf[m4 * 4 + 0] = (mm.x - 1.f) * (1e9f * LOG2E);
      mbf[m4 * 4 + 1] = (mm.y - 1.f) * (1e9f * LOG2E);
      mbf[m4 * 4 + 2] = (mm.z - 1.f) * (1e9f * LOG2E);
      mbf[m4 * 4 + 3] = (mm.w - 1.f) * (1e9f * LOG2E);
    }
    bf16x8 ka0 = *(const bf16x8*)&ks[(k0 + jl) * 40 + 8 * g];
    bf16x8 ka1 = *(const bf16x8*)&ks[(k0 + jl) * 40 + 8 * g + 16];
    bf16x8 va0 = *(const bf16x8*)&vs[jl * 392 + k0 + 8 * g];
    bf16x8 va1 = *(const bf16x8*)&vs[jl * 392 + k0 + 16 + 8 * g];
    #pragma unroll
    for (int jf = 0; jf < 3; ++jf) {
      f32x16 sac;
      #pragma unroll
      for (int r = 0; r < 16; ++r) sac[r] = 0.f;
      __builtin_amdgcn_s_setprio(1);
      sac = __builtin_amdgcn_mfma_f32_32x32x16_bf16(ka0, qf[jf][0], sac, 0, 0, 0);
      sac = __builtin_amdgcn_mfma_f32_32x32x16_bf16(ka1, qf[jf][1], sac, 0, 0, 0);
      __builtin_amdgcn_s_setprio(0);
      // pair bias (bf16, pre-scaled by log2e) + mask bias
      const u16* pbj = pbh + (size_t)(j0 + jf * 32 + jl) * NN + k0 + 4 * g;
      float s[16];
      #pragma unroll
      for (int rr = 0; rr < 4; ++rr) {
        uint2 pv = *(const uint2*)(pbj + 8 * rr);
        s[4 * rr + 0] = sac[4 * rr + 0] + bflo(pv.x) + mbf[4 * rr + 0];
        s[4 * rr + 1] = sac[4 * rr + 1] + bfhi(pv.x) + mbf[4 * rr + 1];
        s[4 * rr + 2] = sac[4 * rr + 2] + bflo(pv.y) + mbf[4 * rr + 2];
        s[4 * rr + 3] = sac[4 * rr + 3] + bfhi(pv.y) + mbf[4 * rr + 3];
      }
      float tmax = s[0];
      #pragma unroll
      for (int r = 1; r < 16; ++r) tmax = fmaxf(tmax, s[r]);
      tmax = fmaxf(tmax, __shfl_xor(tmax, 32, 64));
      float mold = mrun[jf];
      float mnew = fmaxf(mold, tmax);
      float p[16];
      #pragma unroll
      for (int r = 0; r < 16; ++r) p[r] = exp2fast(s[r] - mnew);
      float psum = ((p[0]+p[1])+(p[2]+p[3])) + ((p[4]+p[5])+(p[6]+p[7]))
                 + ((p[8]+p[9])+(p[10]+p[11])) + ((p[12]+p[13])+(p[14]+p[15]));
      if (!__all(mnew == mold)) {
        float rsc = exp2fast(mold - mnew);
        mrun[jf] = mnew;
        lrun[jf] = lrun[jf] * rsc + psum;
        #pragma unroll
        for (int r = 0; r < 16; ++r) oacc[jf][r] *= rsc;
      } else {
        lrun[jf] += psum;
      }
      // P -> bf16 B-operand via permlane32_swap (T12)
      u32 A01 = cvtpk(p[0], p[1]),   A23 = cvtpk(p[2], p[3]);
      u32 B01 = cvtpk(p[4], p[5]),   B23 = cvtpk(p[6], p[7]);
      u32 C01 = cvtpk(p[8], p[9]),   C23 = cvtpk(p[10], p[11]);
      u32 D01 = cvtpk(p[12], p[13]), D23 = cvtpk(p[14], p[15]);
      auto r0 = __builtin_amdgcn_permlane32_swap(A01, B01, false, false);
      auto r1 = __builtin_amdgcn_permlane32_swap(A23, B23, false, false);
      auto r2 = __builtin_amdgcn_permlane32_swap(C01, D01, false, false);
      auto r3 = __builtin_amdgcn_permlane32_swap(C23, D23, false, false);
      union { u32 w[4]; bf16x8 v; } b0, b1;
      b0.w[0] = r0[0]; b0.w[1] = r1[0]; b0.w[2] = r0[1]; b0.w[3] = r1[1];
      b1.w[0] = r2[0]; b1.w[1] = r3[0]; b1.w[2] = r2[1]; b1.w[3] = r3[1];
      __builtin_amdgcn_s_setprio(1);
      oacc[jf] = __builtin_amdgcn_mfma_f32_32x32x16_bf16(va0, b0.v, oacc[jf], 0, 0, 0);
      oacc[jf] = __builtin_amdgcn_mfma_f32_32x32x16_bf16(va1, b1.v, oacc[jf], 0, 0, 0);
      __builtin_amdgcn_s_setprio(0);
    }
  }
  #pragma unroll
  for (int jf = 0; jf < 3; ++jf) {
    float lt = lrun[jf] + __shfl_xor(lrun[jf], 32, 64);
    float inv = 1.f / lt;
    u16* dst = o + (size_t)(i * 384 + j0 + jf * 32 + jl) * CZ + h * 32 + 4 * g;
    #pragma unroll
    for (int q4 = 0; q4 < 4; ++q4) {
      uint2 st;
      st.x = cvtpk(oacc[jf][4 * q4 + 0] * inv, oacc[jf][4 * q4 + 1] * inv);
      st.y = cvtpk(oacc[jf][4 * q4 + 2] * inv, oacc[jf][4 * q4 + 3] * inv);
      *(uint2*)(dst + 8 * q4) = st;
    }
  }
}

// ---------------- Kernel 4: MFMA out = (o*g) @ wo^T + bo  (fp32 out) -------
// 128-row tiles, 4 waves = 4 row-frags; wo + t=o*g staged bf16 swizzled.
__global__ __launch_bounds__(256) void k_out(const u16* __restrict__ o,
    const u16* __restrict__ g, const float* __restrict__ wo,
    const float* __restrict__ bo, float* __restrict__ out) {
  __shared__ __align__(16) u16 wols[128][128];  // 32 KB
  __shared__ __align__(16) u16 tls[128][128];   // 32 KB
  int t = threadIdx.x;
  int lane = t & 63, wid = t >> 6, jl = lane & 31, gg = lane >> 5;
  size_t row0 = (size_t)blockIdx.x * 128;
  #pragma unroll
  for (int it = 0; it < 8; ++it) {
    int idx = t + it * 256; int c = idx >> 4, s = idx & 15;
    float4 f0 = *(const float4*)&wo[c * CZ + s * 8];
    float4 f1 = *(const float4*)&wo[c * CZ + s * 8 + 4];
    uint4 st; st.x = cvtpk(f0.x, f0.y); st.y = cvtpk(f0.z, f0.w);
    st.z = cvtpk(f1.x, f1.y); st.w = cvtpk(f1.z, f1.w);
    *(uint4*)&wols[c][(s ^ (c & 15)) * 8] = st;
  }
  #pragma unroll
  for (int it = 0; it < 8; ++it) {
    int idx = t + it * 256; int r = idx >> 4, s = idx & 15;
    uint4 uo = *(const uint4*)(o + (row0 + r) * CZ + s * 8);
    uint4 ug = *(const uint4*)(g + (row0 + r) * CZ + s * 8);
    uint4 st;
    st.x = cvtpk(bflo(uo.x) * bflo(ug.x), bfhi(uo.x) * bfhi(ug.x));
    st.y = cvtpk(bflo(uo.y) * bflo(ug.y), bfhi(uo.y) * bfhi(ug.y));
    st.z = cvtpk(bflo(uo.z) * bflo(ug.z), bfhi(uo.z) * bfhi(ug.z));
    st.w = cvtpk(bflo(uo.w) * bflo(ug.w), bfhi(uo.w) * bfhi(ug.w));
    *(uint4*)&tls[r][(s ^ (r & 15)) * 8] = st;
  }
  __syncthreads();
  f32x16 acc[4];
  #pragma unroll
  for (int cf = 0; cf < 4; ++cf)
    #pragma unroll
    for (int i = 0; i < 16; ++i) acc[cf][i] = 0.f;
  #pragma unroll
  for (int ks = 0; ks < 8; ++ks) {
    int r = wid * 32 + jl;
    bf16x8 tf = *(const bf16x8*)&tls[r][((2 * ks + gg) ^ (r & 15)) * 8];
    #pragma unroll
    for (int cf = 0; cf < 4; ++cf) {
      int c = cf * 32 + jl;
      bf16x8 wf = *(const bf16x8*)&wols[c][((2 * ks + gg) ^ (c & 15)) * 8];
      acc[cf] = __builtin_amdgcn_mfma_f32_32x32x16_bf16(wf, tf, acc[cf], 0, 0, 0);
    }
  }
  size_t row = row0 + wid * 32 + jl;
  #pragma unroll
  for (int cf = 0; cf < 4; ++cf)
    #pragma unroll
    for (int rr = 0; rr < 4; ++rr) {
      int c = cf * 32 + 8 * rr + 4 * gg;
      float4 bv = *(const float4*)&bo[c];
      float4 v;
      v.x = acc[cf][4 * rr + 0] + bv.x; v.y = acc[cf][4 * rr + 1] + bv.y;
      v.z = acc[cf][4 * rr + 2] + bv.z; v.w = acc[cf][4 * rr + 3] + bv.w;
      *(float4*)&out[row * CZ + c] = v;
    }
}

extern "C" void kernel_launch(void* const* d_in, const int* in_sizes, int n_in,
                              void* d_out, int out_size, void* d_ws, size_t ws_size,
                              hipStream_t stream) {
  const float* act  = (const float*)d_in[0];
  const float* mask = (const float*)d_in[1];
  const float* ln_w = (const float*)d_in[2];
  const float* ln_b = (const float*)d_in[3];
  const float* w2d  = (const float*)d_in[4];
  const float* wq   = (const float*)d_in[5];
  const float* wk   = (const float*)d_in[6];
  const float* wv   = (const float*)d_in[7];
  const float* wg   = (const float*)d_in[8];
  const float* bg   = (const float*)d_in[9];
  const float* wo   = (const float*)d_in[10];
  const float* bo   = (const float*)d_in[11];
  float* out = (float*)d_out;

  char* ws = (char*)d_ws;
  const size_t sz = (size_t)NROWS * CZ * 2;
  u16* xbf = (u16*)ws;
  u16* qb  = (u16*)(ws + 1 * sz);
  u16* kb  = (u16*)(ws + 2 * sz);
  u16* vTb = (u16*)(ws + 3 * sz);
  u16* gb  = (u16*)(ws + 4 * sz);
  u16* ob  = (u16*)(ws + 5 * sz);
  u16* pbf = (u16*)(ws + 6 * sz);

  k_ln<<<NROWS / 4, 256, 0, stream>>>(act, ln_w, ln_b, w2d, xbf, pbf);
  k_projf<<<256, 256, 0, stream>>>(xbf, wq, wk, wv, wg, bg, qb, kb, vTb, gb);
  dim3 ga(NN, NH);
  k_attn<<<ga, 256, 0, stream>>>(qb, kb, vTb, pbf, mask, ob);
  k_out<<<NROWS / 128, 256, 0, stream>>>(ob, gb, wo, bo, out);
}

// Round 4
// 334.007 us; speedup vs baseline: 3.9226x; 1.1647x over previous
//
#include <hip/hip_runtime.h>
#include <hip/hip_bf16.h>

#define NN 384
#define CZ 128
#define NH 4
#define NROWS (NN*NN)
#define LN_EPS 1e-5f
#define LOG2E 1.4426950408889634f
#define QSCALE_L2 (0.17677669529663687f * 1.4426950408889634f)  // 1/sqrt(32) * log2(e)

typedef unsigned short u16;
typedef unsigned int   u32;
typedef __attribute__((ext_vector_type(8))) __bf16 bf16x8;
typedef __attribute__((ext_vector_type(16))) float f32x16;
typedef __attribute__((ext_vector_type(2))) float f32x2;

__device__ __forceinline__ float bflo(u32 u) { union { u32 i; float f; } a; a.i = u << 16; return a.f; }
__device__ __forceinline__ float bfhi(u32 u) { union { u32 i; float f; } a; a.i = u & 0xffff0000u; return a.f; }
__device__ __forceinline__ u32 cvtpk(float lo, float hi) {
  u32 r; asm("v_cvt_pk_bf16_f32 %0, %1, %2" : "=v"(r) : "v"(lo), "v"(hi)); return r;
}
__device__ __forceinline__ float exp2fast(float x) {
  float r; asm("v_exp_f32 %0, %1" : "=v"(r) : "v"(x)); return r;
}
__device__ __forceinline__ float sigm(float x) {
  return 1.f / (1.f + exp2fast(-x * LOG2E));
}
__device__ __forceinline__ f32x2 pkadd(f32x2 a, f32x2 b) {
  f32x2 d; asm("v_pk_add_f32 %0, %1, %2" : "=v"(d) : "v"(a), "v"(b)); return d;
}

// ---------------- Kernel 1: LayerNorm -> x(bf16), pair_bias (fp32*log2e) ---
// half-wave (32 lanes) per row; float4 loads; pb layout [h][r], r=(j,k)
__global__ __launch_bounds__(256) void k_ln(const float* __restrict__ act,
    const float* __restrict__ lnw, const float* __restrict__ lnb,
    const float* __restrict__ w2d, u16* __restrict__ xbf, float* __restrict__ pb) {
  int t = threadIdx.x;
  int l32 = t & 31;
  int r = blockIdx.x * 8 + (t >> 5);
  const float4 a = *(const float4*)(act + (size_t)r * CZ + l32 * 4);
  float s = (a.x + a.y) + (a.z + a.w);
  float s2 = (a.x * a.x + a.y * a.y) + (a.z * a.z + a.w * a.w);
  #pragma unroll
  for (int m = 16; m >= 1; m >>= 1) { s += __shfl_xor(s, m, 32); s2 += __shfl_xor(s2, m, 32); }
  float mu = s * (1.0f / CZ);
  float inv = rsqrtf(s2 * (1.0f / CZ) - mu * mu + LN_EPS);
  float4 w = *(const float4*)(lnw + l32 * 4);
  float4 b = *(const float4*)(lnb + l32 * 4);
  float4 xv;
  xv.x = (a.x - mu) * inv * w.x + b.x;
  xv.y = (a.y - mu) * inv * w.y + b.y;
  xv.z = (a.z - mu) * inv * w.z + b.z;
  xv.w = (a.w - mu) * inv * w.w + b.w;
  uint2 st; st.x = cvtpk(xv.x, xv.y); st.y = cvtpk(xv.z, xv.w);
  *(uint2*)(xbf + (size_t)r * CZ + l32 * 4) = st;
  #pragma unroll
  for (int h = 0; h < NH; ++h) {
    float4 wd = *(const float4*)(w2d + h * CZ + l32 * 4);
    float p = (xv.x * wd.x + xv.y * wd.y) + (xv.z * wd.z + xv.w * wd.w);
    #pragma unroll
    for (int m = 16; m >= 1; m >>= 1) p += __shfl_xor(p, m, 32);
    if (l32 == 0) pb[(size_t)h * NROWS + r] = p * LOG2E;
  }
}

// ---------------- Kernel 2: MFMA projections, one mat per block ------------
// grid (256, 4): blockIdx.y = mat (0=q,1=k,2=v->vT,3=g); 9 tiles of 64 rows.
// LDS: W 32KB + x 16KB = 48KB -> 3 blocks/CU. Wave: rf=wid&1, ef-half=wid>>1.
__global__ __launch_bounds__(256) void k_projf(const u16* __restrict__ x,
    const float* __restrict__ wq, const float* __restrict__ wk,
    const float* __restrict__ wv, const float* __restrict__ wg,
    const float* __restrict__ bg,
    u16* __restrict__ qb, u16* __restrict__ kb,
    u16* __restrict__ vT, u16* __restrict__ gb) {
  __shared__ __align__(16) u16 wl[128][128];  // 32 KB
  __shared__ __align__(16) u16 xl[64][128];   // 16 KB
  int t = threadIdx.x;
  int lane = t & 63, wid = t >> 6;
  int jl = lane & 31, g = lane >> 5;
  int m = blockIdx.y;
  const float* W = (m == 0) ? wq : (m == 1) ? wk : (m == 2) ? wv : wg;
  float sc = (m == 0) ? QSCALE_L2 : 1.f;
  size_t tile0 = (size_t)blockIdx.x * 9;

  uint4 xr[4];
  {
    const uint4* src = (const uint4*)(x + tile0 * 64 * CZ);
    #pragma unroll
    for (int p = 0; p < 4; ++p) xr[p] = src[t + p * 256];
  }
  #pragma unroll
  for (int it = 0; it < 8; ++it) {
    int idx = t + it * 256;
    int e = idx >> 4, s = idx & 15;
    float4 f0 = *(const float4*)&W[e * CZ + s * 8];
    float4 f1 = *(const float4*)&W[e * CZ + s * 8 + 4];
    uint4 st;
    st.x = cvtpk(f0.x * sc, f0.y * sc); st.y = cvtpk(f0.z * sc, f0.w * sc);
    st.z = cvtpk(f1.x * sc, f1.y * sc); st.w = cvtpk(f1.z * sc, f1.w * sc);
    *(uint4*)&wl[e][(s ^ (e & 15)) * 8] = st;
  }

  int rfb = (wid & 1) * 32, efb = (wid >> 1) * 2;
  for (int it = 0; it < 9; ++it) {
    __syncthreads();
    #pragma unroll
    for (int p = 0; p < 4; ++p) {
      int q = t + p * 256; int r = q >> 4, s = q & 15;
      *(uint4*)&xl[r][(s ^ (r & 15)) * 8] = xr[p];
    }
    __syncthreads();
    if (it < 8) {
      const uint4* src = (const uint4*)(x + (tile0 + it + 1) * 64 * CZ);
      #pragma unroll
      for (int p = 0; p < 4; ++p) xr[p] = src[t + p * 256];
    }
    size_t row0 = (tile0 + it) * 64;

    f32x16 acc[2];
    #pragma unroll
    for (int ef = 0; ef < 2; ++ef)
      #pragma unroll
      for (int i = 0; i < 16; ++i) acc[ef][i] = 0.f;

    if (m == 2) {  // v: mfma(x, W^T) -> C lane = e, regs = row
      #pragma unroll
      for (int ks = 0; ks < 8; ++ks) {
        int r = rfb + jl;
        bf16x8 xa = *(const bf16x8*)&xl[r][((2 * ks + g) ^ (r & 15)) * 8];
        #pragma unroll
        for (int ef = 0; ef < 2; ++ef) {
          int e = (efb + ef) * 32 + jl;
          bf16x8 wf = *(const bf16x8*)&wl[e][((2 * ks + g) ^ (e & 15)) * 8];
          acc[ef] = __builtin_amdgcn_mfma_f32_32x32x16_bf16(xa, wf, acc[ef], 0, 0, 0);
        }
      }
      #pragma unroll
      for (int ef = 0; ef < 2; ++ef) {
        int e = (efb + ef) * 32 + jl;
        u16* dst = vT + (size_t)e * NROWS + row0 + rfb + 4 * g;
        #pragma unroll
        for (int rr = 0; rr < 4; ++rr) {
          uint2 st;
          st.x = cvtpk(acc[ef][4 * rr + 0], acc[ef][4 * rr + 1]);
          st.y = cvtpk(acc[ef][4 * rr + 2], acc[ef][4 * rr + 3]);
          *(uint2*)(dst + 8 * rr) = st;
        }
      }
    } else {  // q/k/g: mfma(W, x^T) -> C lane = row, regs = e
      #pragma unroll
      for (int ks = 0; ks < 8; ++ks) {
        int r = rfb + jl;
        bf16x8 xa = *(const bf16x8*)&xl[r][((2 * ks + g) ^ (r & 15)) * 8];
        #pragma unroll
        for (int ef = 0; ef < 2; ++ef) {
          int e = (efb + ef) * 32 + jl;
          bf16x8 wf = *(const bf16x8*)&wl[e][((2 * ks + g) ^ (e & 15)) * 8];
          acc[ef] = __builtin_amdgcn_mfma_f32_32x32x16_bf16(wf, xa, acc[ef], 0, 0, 0);
        }
      }
      u16* ob = (m == 0) ? qb : (m == 1) ? kb : gb;
      size_t row = row0 + rfb + jl;
      #pragma unroll
      for (int ef = 0; ef < 2; ++ef) {
        u16* dst = ob + row * CZ + (efb + ef) * 32 + 4 * g;
        #pragma unroll
        for (int rr = 0; rr < 4; ++rr) {
          float v0 = acc[ef][4 * rr + 0], v1 = acc[ef][4 * rr + 1];
          float v2 = acc[ef][4 * rr + 2], v3 = acc[ef][4 * rr + 3];
          if (m == 3) {
            float4 bv = *(const float4*)&bg[(efb + ef) * 32 + 8 * rr + 4 * g];
            v0 = sigm(v0 + bv.x); v1 = sigm(v1 + bv.y);
            v2 = sigm(v2 + bv.z); v3 = sigm(v3 + bv.w);
          }
          uint2 st; st.x = cvtpk(v0, v1); st.y = cvtpk(v2, v3);
          *(uint2*)(dst + 8 * rr) = st;
        }
      }
    }
  }
}

// ---------------- Kernel 3: MFMA row attention, online softmax -------------
// block (i,h), 4 waves, wave owns 96 j. LDS 48KB: K,V in [12][32][4 slot]
// XOR-swizzled 16B slots -> 3 blocks/CU. pk-add softmax, nomask fast path,
// defer-max (THR=8 in log2 domain).
__global__ __launch_bounds__(256) void k_attn(const u16* __restrict__ q,
    const u16* __restrict__ kmat, const u16* __restrict__ vT,
    const float* __restrict__ pb, const float* __restrict__ mask,
    u16* __restrict__ o) {
  __shared__ __align__(16) u16 lds[24576];  // K u16[0,12288), V [12288,24576)
  int i = blockIdx.x, h = blockIdx.y;
  int t = threadIdx.x;
  size_t base = ((size_t)i * 384) * CZ + h * 32;
  {
    const u16* src = kmat + base;
    for (int idx = t; idx < 1536; idx += 256) {
      int r = idx >> 2, c = idx & 3;
      uint4 u = *(const uint4*)(src + (size_t)r * CZ + c * 8);
      *(uint4*)&lds[(r >> 5) * 1024 + (r & 31) * 32 + ((c ^ (r & 3)) * 8)] = u;
    }
  }
  {
    const u16* src = vT + (size_t)(h * 32) * NROWS + (size_t)i * 384;
    for (int idx = t; idx < 1536; idx += 256) {
      int d = idx / 48, c = idx % 48;
      uint4 u = *(const uint4*)(src + (size_t)d * NROWS + c * 8);
      *(uint4*)&lds[12288 + (c >> 2) * 1024 + d * 32 + (((c & 3) ^ (d & 3)) * 8)] = u;
    }
  }
  __syncthreads();
  int lane = t & 63, wid = t >> 6;
  int jl = lane & 31, g = lane >> 5;
  int j0 = wid * 96;
  bf16x8 qf[3][2];
  const u16* qbase = q + base;
  #pragma unroll
  for (int jf = 0; jf < 3; ++jf)
    #pragma unroll
    for (int s = 0; s < 2; ++s)
      qf[jf][s] = *(const bf16x8*)(qbase + (size_t)(j0 + jf * 32 + jl) * CZ + g * 8 + s * 16);

  f32x16 oacc[3];
  #pragma unroll
  for (int jf = 0; jf < 3; ++jf)
    #pragma unroll
    for (int r = 0; r < 16; ++r) oacc[jf][r] = 0.f;
  float mrun[3] = {-3e38f, -3e38f, -3e38f};
  float lrun[3] = {0.f, 0.f, 0.f};
  const float* pbh = pb + (size_t)h * NROWS;
  const float* mrow = mask + (size_t)i * NN;

  for (int k0 = 0; k0 < NN; k0 += 32) {
    int kt = k0 >> 5;
    // mask tile: nomask fast path (wave-uniform)
    float4 mm[4];
    #pragma unroll
    for (int m4 = 0; m4 < 4; ++m4) mm[m4] = *(const float4*)(mrow + k0 + 8 * m4 + 4 * g);
    bool ok = (mm[0].x == 1.f) & (mm[0].y == 1.f) & (mm[0].z == 1.f) & (mm[0].w == 1.f)
            & (mm[1].x == 1.f) & (mm[1].y == 1.f) & (mm[1].z == 1.f) & (mm[1].w == 1.f)
            & (mm[2].x == 1.f) & (mm[2].y == 1.f) & (mm[2].z == 1.f) & (mm[2].w == 1.f)
            & (mm[3].x == 1.f) & (mm[3].y == 1.f) & (mm[3].z == 1.f) & (mm[3].w == 1.f);
    bool nm = __all(ok);
    f32x2 mb2[8];
    if (!nm) {
      #pragma unroll
      for (int m4 = 0; m4 < 4; ++m4) {
        mb2[2 * m4 + 0] = f32x2{(mm[m4].x - 1.f) * (1e9f * LOG2E), (mm[m4].y - 1.f) * (1e9f * LOG2E)};
        mb2[2 * m4 + 1] = f32x2{(mm[m4].z - 1.f) * (1e9f * LOG2E), (mm[m4].w - 1.f) * (1e9f * LOG2E)};
      }
    }
    bf16x8 ka0 = *(const bf16x8*)&lds[kt * 1024 + jl * 32 + ((g ^ (jl & 3)) * 8)];
    bf16x8 ka1 = *(const bf16x8*)&lds[kt * 1024 + jl * 32 + (((g + 2) ^ (jl & 3)) * 8)];
    bf16x8 va0 = *(const bf16x8*)&lds[12288 + kt * 1024 + jl * 32 + ((g ^ (jl & 3)) * 8)];
    bf16x8 va1 = *(const bf16x8*)&lds[12288 + kt * 1024 + jl * 32 + (((g + 2) ^ (jl & 3)) * 8)];
    #pragma unroll
    for (int jf = 0; jf < 3; ++jf) {
      f32x16 sac;
      #pragma unroll
      for (int r = 0; r < 16; ++r) sac[r] = 0.f;
      __builtin_amdgcn_s_setprio(1);
      sac = __builtin_amdgcn_mfma_f32_32x32x16_bf16(ka0, qf[jf][0], sac, 0, 0, 0);
      sac = __builtin_amdgcn_mfma_f32_32x32x16_bf16(ka1, qf[jf][1], sac, 0, 0, 0);
      __builtin_amdgcn_s_setprio(0);
      const float* pbj = pbh + (size_t)(j0 + jf * 32 + jl) * NN + k0 + 4 * g;
      f32x2 s2[8];
      #pragma unroll
      for (int rr = 0; rr < 4; ++rr) {
        float4 pv = *(const float4*)(pbj + 8 * rr);
        s2[2 * rr + 0] = pkadd(f32x2{sac[4 * rr + 0], sac[4 * rr + 1]}, f32x2{pv.x, pv.y});
        s2[2 * rr + 1] = pkadd(f32x2{sac[4 * rr + 2], sac[4 * rr + 3]}, f32x2{pv.z, pv.w});
      }
      if (!nm) {
        #pragma unroll
        for (int p8 = 0; p8 < 8; ++p8) s2[p8] = pkadd(s2[p8], mb2[p8]);
      }
      float t0 = fmaxf(fmaxf(s2[0][0], s2[0][1]), fmaxf(s2[1][0], s2[1][1]));
      float t1 = fmaxf(fmaxf(s2[2][0], s2[2][1]), fmaxf(s2[3][0], s2[3][1]));
      float t2 = fmaxf(fmaxf(s2[4][0], s2[4][1]), fmaxf(s2[5][0], s2[5][1]));
      float t3 = fmaxf(fmaxf(s2[6][0], s2[6][1]), fmaxf(s2[7][0], s2[7][1]));
      float tmax = fmaxf(fmaxf(t0, t1), fmaxf(t2, t3));
      tmax = fmaxf(tmax, __shfl_xor(tmax, 32, 64));
      float mold = mrun[jf];
      bool defer = __all(tmax <= mold + 8.f);
      float mnew = defer ? mold : fmaxf(mold, tmax);
      f32x2 nmw = f32x2{-mnew, -mnew};
      f32x2 p2[8];
      #pragma unroll
      for (int p8 = 0; p8 < 8; ++p8) {
        f32x2 d = pkadd(s2[p8], nmw);
        p2[p8] = f32x2{exp2fast(d[0]), exp2fast(d[1])};
      }
      f32x2 q0 = pkadd(p2[0], p2[1]), q1 = pkadd(p2[2], p2[3]);
      f32x2 q2 = pkadd(p2[4], p2[5]), q3 = pkadd(p2[6], p2[7]);
      q0 = pkadd(q0, q1); q2 = pkadd(q2, q3); q0 = pkadd(q0, q2);
      float psum = q0[0] + q0[1];
      if (!defer) {
        float rsc = exp2fast(mold - mnew);
        mrun[jf] = mnew;
        lrun[jf] = lrun[jf] * rsc + psum;
        #pragma unroll
        for (int r = 0; r < 16; ++r) oacc[jf][r] *= rsc;
      } else {
        lrun[jf] += psum;
      }
      u32 A01 = cvtpk(p2[0][0], p2[0][1]), A23 = cvtpk(p2[1][0], p2[1][1]);
      u32 B01 = cvtpk(p2[2][0], p2[2][1]), B23 = cvtpk(p2[3][0], p2[3][1]);
      u32 C01 = cvtpk(p2[4][0], p2[4][1]), C23 = cvtpk(p2[5][0], p2[5][1]);
      u32 D01 = cvtpk(p2[6][0], p2[6][1]), D23 = cvtpk(p2[7][0], p2[7][1]);
      auto r0 = __builtin_amdgcn_permlane32_swap(A01, B01, false, false);
      auto r1 = __builtin_amdgcn_permlane32_swap(A23, B23, false, false);
      auto r2 = __builtin_amdgcn_permlane32_swap(C01, D01, false, false);
      auto r3 = __builtin_amdgcn_permlane32_swap(C23, D23, false, false);
      union { u32 w[4]; bf16x8 v; } b0, b1;
      b0.w[0] = r0[0]; b0.w[1] = r1[0]; b0.w[2] = r0[1]; b0.w[3] = r1[1];
      b1.w[0] = r2[0]; b1.w[1] = r3[0]; b1.w[2] = r2[1]; b1.w[3] = r3[1];
      __builtin_amdgcn_s_setprio(1);
      oacc[jf] = __builtin_amdgcn_mfma_f32_32x32x16_bf16(va0, b0.v, oacc[jf], 0, 0, 0);
      oacc[jf] = __builtin_amdgcn_mfma_f32_32x32x16_bf16(va1, b1.v, oacc[jf], 0, 0, 0);
      __builtin_amdgcn_s_setprio(0);
    }
  }
  #pragma unroll
  for (int jf = 0; jf < 3; ++jf) {
    float lt = lrun[jf] + __shfl_xor(lrun[jf], 32, 64);
    float inv = 1.f / lt;
    u16* dst = o + (size_t)(i * 384 + j0 + jf * 32 + jl) * CZ + h * 32 + 4 * g;
    #pragma unroll
    for (int q4 = 0; q4 < 4; ++q4) {
      uint2 st;
      st.x = cvtpk(oacc[jf][4 * q4 + 0] * inv, oacc[jf][4 * q4 + 1] * inv);
      st.y = cvtpk(oacc[jf][4 * q4 + 2] * inv, oacc[jf][4 * q4 + 3] * inv);
      *(uint2*)(dst + 8 * q4) = st;
    }
  }
}

// ---------------- Kernel 4: MFMA out = (o*g) @ wo^T + bo  (fp32 out) -------
__global__ __launch_bounds__(256) void k_out(const u16* __restrict__ o,
    const u16* __restrict__ g, const float* __restrict__ wo,
    const float* __restrict__ bo, float* __restrict__ out) {
  __shared__ __align__(16) u16 wols[128][128];  // 32 KB
  __shared__ __align__(16) u16 tls[128][128];   // 32 KB
  int t = threadIdx.x;
  int lane = t & 63, wid = t >> 6, jl = lane & 31, gg = lane >> 5;
  size_t row0 = (size_t)blockIdx.x * 128;
  #pragma unroll
  for (int it = 0; it < 8; ++it) {
    int idx = t + it * 256; int c = idx >> 4, s = idx & 15;
    float4 f0 = *(const float4*)&wo[c * CZ + s * 8];
    float4 f1 = *(const float4*)&wo[c * CZ + s * 8 + 4];
    uint4 st; st.x = cvtpk(f0.x, f0.y); st.y = cvtpk(f0.z, f0.w);
    st.z = cvtpk(f1.x, f1.y); st.w = cvtpk(f1.z, f1.w);
    *(uint4*)&wols[c][(s ^ (c & 15)) * 8] = st;
  }
  #pragma unroll
  for (int it = 0; it < 8; ++it) {
    int idx = t + it * 256; int r = idx >> 4, s = idx & 15;
    uint4 uo = *(const uint4*)(o + (row0 + r) * CZ + s * 8);
    uint4 ug = *(const uint4*)(g + (row0 + r) * CZ + s * 8);
    uint4 st;
    st.x = cvtpk(bflo(uo.x) * bflo(ug.x), bfhi(uo.x) * bfhi(ug.x));
    st.y = cvtpk(bflo(uo.y) * bflo(ug.y), bfhi(uo.y) * bfhi(ug.y));
    st.z = cvtpk(bflo(uo.z) * bflo(ug.z), bfhi(uo.z) * bfhi(ug.z));
    st.w = cvtpk(bflo(uo.w) * bflo(ug.w), bfhi(uo.w) * bfhi(ug.w));
    *(uint4*)&tls[r][(s ^ (r & 15)) * 8] = st;
  }
  __syncthreads();
  f32x16 acc[4];
  #pragma unroll
  for (int cf = 0; cf < 4; ++cf)
    #pragma unroll
    for (int i = 0; i < 16; ++i) acc[cf][i] = 0.f;
  #pragma unroll
  for (int ks = 0; ks < 8; ++ks) {
    int r = wid * 32 + jl;
    bf16x8 tf = *(const bf16x8*)&tls[r][((2 * ks + gg) ^ (r & 15)) * 8];
    #pragma unroll
    for (int cf = 0; cf < 4; ++cf) {
      int c = cf * 32 + jl;
      bf16x8 wf = *(const bf16x8*)&wols[c][((2 * ks + gg) ^ (c & 15)) * 8];
      acc[cf] = __builtin_amdgcn_mfma_f32_32x32x16_bf16(wf, tf, acc[cf], 0, 0, 0);
    }
  }
  size_t row = row0 + wid * 32 + jl;
  #pragma unroll
  for (int cf = 0; cf < 4; ++cf)
    #pragma unroll
    for (int rr = 0; rr < 4; ++rr) {
      int c = cf * 32 + 8 * rr + 4 * gg;
      float4 bv = *(const float4*)&bo[c];
      float4 v;
      v.x = acc[cf][4 * rr + 0] + bv.x; v.y = acc[cf][4 * rr + 1] + bv.y;
      v.z = acc[cf][4 * rr + 2] + bv.z; v.w = acc[cf][4 * rr + 3] + bv.w;
      *(float4*)&out[row * CZ + c] = v;
    }
}

extern "C" void kernel_launch(void* const* d_in, const int* in_sizes, int n_in,
                              void* d_out, int out_size, void* d_ws, size_t ws_size,
                              hipStream_t stream) {
  const float* act  = (const float*)d_in[0];
  const float* mask = (const float*)d_in[1];
  const float* ln_w = (const float*)d_in[2];
  const float* ln_b = (const float*)d_in[3];
  const float* w2d  = (const float*)d_in[4];
  const float* wq   = (const float*)d_in[5];
  const float* wk   = (const float*)d_in[6];
  const float* wv   = (const float*)d_in[7];
  const float* wg   = (const float*)d_in[8];
  const float* bg   = (const float*)d_in[9];
  const float* wo   = (const float*)d_in[10];
  const float* bo   = (const float*)d_in[11];
  float* out = (float*)d_out;

  char* ws = (char*)d_ws;
  const size_t sz = (size_t)NROWS * CZ * 2;
  u16* xbf = (u16*)ws;
  u16* qb  = (u16*)(ws + 1 * sz);
  u16* kb  = (u16*)(ws + 2 * sz);
  u16* vTb = (u16*)(ws + 3 * sz);
  u16* gb  = (u16*)(ws + 4 * sz);
  u16* ob  = (u16*)(ws + 5 * sz);
  float* pbf = (float*)(ws + 6 * sz);

  k_ln<<<NROWS / 8, 256, 0, stream>>>(act, ln_w, ln_b, w2d, xbf, pbf);
  dim3 gp(256, 4);
  k_projf<<<gp, 256, 0, stream>>>(xbf, wq, wk, wv, wg, bg, qb, kb, vTb, gb);
  dim3 ga(NN, NH);
  k_attn<<<ga, 256, 0, stream>>>(qb, kb, vTb, pbf, mask, ob);
  k_out<<<NROWS / 128, 256, 0, stream>>>(ob, gb, wo, bo, out);
}